// Round 1
// baseline (384.516 us; speedup 1.0000x reference)
//
#include <hip/hip_runtime.h>
#include <math.h>

// Problem constants
#define BB 8
#define CC 64
#define OO 64
#define HH 128
#define WW 128
#define HW (HH*WW)              // 16384
#define NPIX (BB*HW)            // 131072

// Workspace layout (floats)
//  xt : x transposed to NHWC            [B][H][W][C]      8388608
//  om : offset(18)+mask(9) per pixel    [NPIX][28]        3670016
//  wt : w_main repacked [k][c][o]                         36864
//  wb : w_offset||w_mask repacked [tap][o27][c]           15552
#define XT_OFF   0
#define OM_OFF   8388608
#define WT_OFF   (OM_OFF + NPIX*28)          // 12058624
#define WB_OFF   (WT_OFF + 36864)            // 12095488

// ---------------------------------------------------------------------------
// Kernel 1: NCHW -> NHWC transpose of x (tiled, 32x32 per block)
// grid: (B*H, W/32, C/32), block (32,8)
// ---------------------------------------------------------------------------
__global__ __launch_bounds__(256) void transpose_kernel(
    const float* __restrict__ x, float* __restrict__ xt)
{
    __shared__ float tile[32][33];
    int bh = blockIdx.x;            // b*128 + h
    int w0 = blockIdx.y * 32;
    int c0 = blockIdx.z * 32;
    int b  = bh >> 7;
    int h  = bh & 127;
    int tx = threadIdx.x;           // 0..31
    int ty = threadIdx.y;           // 0..7

    // read x[b][c0+ty+8j][h][w0+tx]  (coalesced along w)
    #pragma unroll
    for (int j = 0; j < 4; ++j) {
        int c = c0 + ty + 8*j;
        tile[ty + 8*j][tx] = x[(((size_t)(b*CC + c))*HH + h)*WW + (w0 + tx)];
    }
    __syncthreads();
    // write xt[b][h][w0+ty+8j][c0+tx]  (coalesced along c)
    #pragma unroll
    for (int j = 0; j < 4; ++j) {
        int w = w0 + ty + 8*j;
        xt[(((size_t)(b*HH + h))*WW + w)*CC + (c0 + tx)] = tile[tx][ty + 8*j];
    }
}

// ---------------------------------------------------------------------------
// Kernel 2: weight repacks
//   wt[k*4096 + c*64 + o] = w_main[o*576 + c*9 + k]
//   wb[k*1728 + o*64 + c] = (o<18 ? w_offset : w_mask)[...]
// grid: ceil(52416/256) blocks
// ---------------------------------------------------------------------------
__global__ __launch_bounds__(256) void repack_kernel(
    const float* __restrict__ wm, const float* __restrict__ woff,
    const float* __restrict__ wmask, float* __restrict__ wt, float* __restrict__ wb)
{
    int i = blockIdx.x * 256 + threadIdx.x;
    if (i < 36864) {
        int o = i / 576; int r = i % 576; int c = r / 9; int k = r % 9;
        wt[k*4096 + c*64 + o] = wm[i];
    }
    int j = i - 36864;
    if (j >= 0 && j < 15552) {
        int o = j / 576; int r = j % 576; int c = r / 9; int k = r % 9;
        float v = (o < 18) ? woff[j] : wmask[j - 18*576];
        wb[k*1728 + o*64 + c] = v;
    }
}

// ---------------------------------------------------------------------------
// Kernel 3: conv3x3 producing 18 offset + 9 mask(sigmoid) channels per pixel
// thread per pixel; weights read uniform (scalar-cache path) from wb[tap][o][c]
// grid: NPIX/256 blocks
// ---------------------------------------------------------------------------
__global__ __launch_bounds__(256) void conv27_kernel(
    const float* __restrict__ xt, const float* __restrict__ wb,
    const float* __restrict__ boff, const float* __restrict__ bmsk,
    float* __restrict__ om)
{
    int pid = blockIdx.x * 256 + threadIdx.x;
    int b = pid >> 14;
    int h = (pid >> 7) & 127;
    int w = pid & 127;

    float acc[27];
    #pragma unroll
    for (int o = 0; o < 27; ++o) acc[o] = 0.f;

    for (int kh = 0; kh < 3; ++kh) {
        int y = h + kh - 1;
        if ((unsigned)y >= (unsigned)HH) continue;   // wave-uniform (h uniform per wave)
        #pragma unroll
        for (int kw = 0; kw < 3; ++kw) {
            int xx = w + kw - 1;
            if ((unsigned)xx >= (unsigned)WW) continue;  // divergent only at tile edges
            int tap = kh*3 + kw;
            const float4* xp = (const float4*)(xt + ((size_t)((b*HH + y)*WW + xx))*CC);
            const float4* wp = (const float4*)(wb + tap*1728);
            for (int cg = 0; cg < 16; ++cg) {
                float4 xv = xp[cg];
                #pragma unroll
                for (int o = 0; o < 27; ++o) {
                    float4 wv = wp[o*16 + cg];   // uniform address -> s_load
                    acc[o] += xv.x*wv.x + xv.y*wv.y + xv.z*wv.z + xv.w*wv.w;
                }
            }
        }
    }

    float* dst = om + (size_t)pid * 28;
    #pragma unroll
    for (int o = 0; o < 18; ++o) dst[o] = acc[o] + boff[o];
    #pragma unroll
    for (int j = 0; j < 9; ++j) {
        float a = acc[18 + j] + bmsk[j];
        dst[18 + j] = 1.f / (1.f + expf(-a));
    }
}

// ---------------------------------------------------------------------------
// Kernel 4: deformable sampling + GEMM (M=NPIX, K=576, N=64)
// block = 256 threads, 64 consecutive pixels (same b,h row).
// per k (9 taps): phase A -> samp[c][p] in LDS; phase B -> acc[16] per thread
// (lane = pixel, wave = 16 output channels, weights wave-uniform -> sgpr)
// ---------------------------------------------------------------------------
__global__ __launch_bounds__(256) void deform_kernel(
    const float* __restrict__ xt, const float* __restrict__ om,
    const float* __restrict__ wt, float* __restrict__ out)
{
    __shared__ float samp[64*64];     // [c][p]

    int t    = threadIdx.x;
    int lane = t & 63;
    int wave = __builtin_amdgcn_readfirstlane(t >> 6);
    int p0   = blockIdx.x * 64;

    // phase-A role: 4 lanes per pixel, each covers 16 channels
    int pa = t >> 2;                  // pixel slot 0..63
    int cg = t & 3;                   // channel group (16 floats)
    int gp_a = p0 + pa;
    int b_a = gp_a >> 14;
    int h_a = (gp_a >> 7) & 127;
    int w_a = gp_a & 127;
    const float* omp = om + (size_t)gp_a * 28;

    float acc[16];
    #pragma unroll
    for (int i = 0; i < 16; ++i) acc[i] = 0.f;

    for (int k = 0; k < 9; ++k) {
        // ---------------- phase A: bilinear sampling ----------------
        float dy = omp[2*k];
        float dx = omp[2*k + 1];
        float m  = omp[18 + k];
        float py = (float)(h_a + (k/3) - 1) + dy;
        float px = (float)(w_a + (k%3) - 1) + dx;
        float y0f = floorf(py), x0f = floorf(px);
        float ly = py - y0f,  lx = px - x0f;
        int y0 = (int)y0f, x0 = (int)x0f;
        int y1 = y0 + 1,   x1 = x0 + 1;

        float vy0 = ((unsigned)y0 < (unsigned)HH) ? 1.f : 0.f;
        float vy1 = ((unsigned)y1 < (unsigned)HH) ? 1.f : 0.f;
        float vx0 = ((unsigned)x0 < (unsigned)WW) ? 1.f : 0.f;
        float vx1 = ((unsigned)x1 < (unsigned)WW) ? 1.f : 0.f;

        int ys[4] = { y0, y0, y1, y1 };
        int xs[4] = { x0, x1, x0, x1 };
        float cw[4] = { (1.f-ly)*(1.f-lx)*vy0*vx0*m,
                        (1.f-ly)*lx      *vy0*vx1*m,
                        ly*(1.f-lx)      *vy1*vx0*m,
                        ly*lx            *vy1*vx1*m };

        float v[16];
        #pragma unroll
        for (int i = 0; i < 16; ++i) v[i] = 0.f;

        #pragma unroll
        for (int cn = 0; cn < 4; ++cn) {
            int yc = min(max(ys[cn], 0), HH-1);
            int xc = min(max(xs[cn], 0), WW-1);
            float wgt = cw[cn];
            const float4* cp = (const float4*)(xt +
                ((size_t)((b_a*HH + yc)*WW + xc))*CC + cg*16);
            float4 aa[4];
            aa[0] = cp[0]; aa[1] = cp[1]; aa[2] = cp[2]; aa[3] = cp[3];
            const float* af = reinterpret_cast<const float*>(aa);
            #pragma unroll
            for (int j = 0; j < 16; ++j) v[j] += wgt * af[j];
        }

        __syncthreads();   // previous phase B done reading samp
        #pragma unroll
        for (int j = 0; j < 16; ++j) samp[(cg*16 + j)*64 + pa] = v[j];
        __syncthreads();

        // ---------------- phase B: GEMM accumulate ----------------
        const float* wk = wt + k*4096;          // [c][o]
        int o0 = wave * 16;
        #pragma unroll 4
        for (int c = 0; c < 64; ++c) {
            float s = samp[c*64 + lane];        // stride-1 across lanes
            const float* wc = wk + c*64 + o0;   // wave-uniform -> s_load
            #pragma unroll
            for (int j = 0; j < 16; ++j) acc[j] += s * wc[j];
        }
    }

    // ---------------- store: out[b][o][h][w], o = wave*16 + j ----------------
    int gp  = p0 + lane;
    int b   = gp >> 14;
    int hw_ = gp & 16383;
    float* op = out + (size_t)b*OO*HW + hw_;
    #pragma unroll
    for (int j = 0; j < 16; ++j) op[(size_t)(wave*16 + j)*HW] = acc[j];
}

// ---------------------------------------------------------------------------
extern "C" void kernel_launch(void* const* d_in, const int* in_sizes, int n_in,
                              void* d_out, int out_size, void* d_ws, size_t ws_size,
                              hipStream_t stream)
{
    const float* x      = (const float*)d_in[0];
    const float* w_main = (const float*)d_in[1];
    const float* w_off  = (const float*)d_in[2];
    const float* b_off  = (const float*)d_in[3];
    const float* w_msk  = (const float*)d_in[4];
    const float* b_msk  = (const float*)d_in[5];
    float* out = (float*)d_out;

    float* ws = (float*)d_ws;
    float* xt = ws + XT_OFF;
    float* om = ws + OM_OFF;
    float* wt = ws + WT_OFF;
    float* wb = ws + WB_OFF;

    // 1. transpose x -> NHWC
    dim3 tgrid(BB*HH, WW/32, CC/32);
    dim3 tblock(32, 8);
    transpose_kernel<<<tgrid, tblock, 0, stream>>>(x, xt);

    // 2. repack weights
    repack_kernel<<<(36864 + 15552 + 255)/256, 256, 0, stream>>>(
        w_main, w_off, w_msk, wt, wb);

    // 3. offset + mask conv
    conv27_kernel<<<NPIX/256, 256, 0, stream>>>(xt, wb, b_off, b_msk, om);

    // 4. deformable conv
    deform_kernel<<<NPIX/64, 256, 0, stream>>>(xt, om, wt, out);
}

// Round 3
// 194.301 us; speedup vs baseline: 1.9790x; 1.9790x over previous
//
#include <hip/hip_runtime.h>
#include <math.h>

#define BB 8
#define CC 64
#define OO 64
#define HH 128
#define WW 128
#define HW (HH*WW)              // 16384
#define NPIX (BB*HW)            // 131072

typedef __bf16 bf16x8 __attribute__((ext_vector_type(8)));
typedef float floatx4 __attribute__((ext_vector_type(4)));
typedef unsigned short ushort_t;

// Workspace layout (bytes):
//  xt : bf16 NHWC [B][H][W][64]        16777216
//  om : fp32 [NPIX][28]                14680064
//  wt : bf16 [64][576]  (o, tap*64+c)     73728
//  wb : bf16 [32][576]  (o27pad, k)       36864
#define XT_BYTES  16777216
#define OM_BYTES  14680064
#define WT_BYTES  73728

__device__ __forceinline__ unsigned short f2b(float f) {
    unsigned u = __float_as_uint(f);
    u += 0x7fffu + ((u >> 16) & 1u);       // round-to-nearest-even
    return (unsigned short)(u >> 16);
}

__device__ __forceinline__ void unpack8(uint4 q, float* f) {
    f[0] = __uint_as_float(q.x << 16); f[1] = __uint_as_float(q.x & 0xffff0000u);
    f[2] = __uint_as_float(q.y << 16); f[3] = __uint_as_float(q.y & 0xffff0000u);
    f[4] = __uint_as_float(q.z << 16); f[5] = __uint_as_float(q.z & 0xffff0000u);
    f[6] = __uint_as_float(q.w << 16); f[7] = __uint_as_float(q.w & 0xffff0000u);
}

// ---------------------------------------------------------------------------
// Kernel 1: NCHW fp32 -> NHWC bf16 transpose
// ---------------------------------------------------------------------------
__global__ __launch_bounds__(256) void transpose_kernel(
    const float* __restrict__ x, ushort_t* __restrict__ xt)
{
    __shared__ float tile[32][33];
    int bh = blockIdx.x;
    int w0 = blockIdx.y * 32;
    int c0 = blockIdx.z * 32;
    int b  = bh >> 7;
    int h  = bh & 127;
    int tx = threadIdx.x;
    int ty = threadIdx.y;

    #pragma unroll
    for (int j = 0; j < 4; ++j) {
        int c = c0 + ty + 8*j;
        tile[ty + 8*j][tx] = x[(((size_t)(b*CC + c))*HH + h)*WW + (w0 + tx)];
    }
    __syncthreads();
    #pragma unroll
    for (int j = 0; j < 4; ++j) {
        int w = w0 + ty + 8*j;
        xt[(((size_t)(b*HH + h))*WW + w)*CC + (c0 + tx)] = f2b(tile[tx][ty + 8*j]);
    }
}

// ---------------------------------------------------------------------------
// Kernel 2: weight repack to bf16
// ---------------------------------------------------------------------------
__global__ __launch_bounds__(256) void repack_kernel(
    const float* __restrict__ wm, const float* __restrict__ woff,
    const float* __restrict__ wmask, ushort_t* __restrict__ wt,
    ushort_t* __restrict__ wb)
{
    int i = blockIdx.x * 256 + threadIdx.x;
    if (i < 36864) {
        int o = i / 576, k = i % 576, tap = k >> 6, c = k & 63;
        wt[i] = f2b(wm[o*576 + c*9 + tap]);
    }
    int j = i - 36864;
    if (j >= 0 && j < 18432) {
        int o = j / 576, k = j % 576, tap = k >> 6, c = k & 63;
        float v = 0.f;
        if (o < 18)      v = woff[o*576 + c*9 + tap];
        else if (o < 27) v = wmask[(o-18)*576 + c*9 + tap];
        wb[j] = f2b(v);
    }
}

// ---------------------------------------------------------------------------
// Kernel 3: conv3x3 -> 18 offsets + 9 sigmoid masks, via bf16 MFMA
// ---------------------------------------------------------------------------
__global__ __launch_bounds__(256) void conv27_kernel(
    const ushort_t* __restrict__ xt, const ushort_t* __restrict__ wb,
    const float* __restrict__ boff, const float* __restrict__ bmsk,
    float* __restrict__ om)
{
    __shared__ ushort_t win[3*66*72];
    int p0 = blockIdx.x * 64;
    int b = p0 >> 14, h = (p0 >> 7) & 127, w0 = p0 & 127;
    int t = threadIdx.x;

    for (int idx = t; idx < 1584; idx += 256) {
        int r   = idx / 528;            // 66*8
        int rem = idx - r*528;
        int col = rem >> 3;
        int ch  = (rem & 7) << 3;
        int y = h + r - 1, x = w0 + col - 1;
        uint4 val = make_uint4(0,0,0,0);
        if ((unsigned)y < (unsigned)HH && (unsigned)x < (unsigned)WW)
            val = *(const uint4*)(xt + ((((size_t)b*HH + y)*WW + x) << 6) + ch);
        *(uint4*)(win + (r*66 + col)*72 + ch) = val;
    }
    __syncthreads();

    int lane = t & 63, wv = t >> 6;
    int n = lane & 15, quad = lane >> 4;
    floatx4 acc0 = {0.f,0.f,0.f,0.f}, acc1 = {0.f,0.f,0.f,0.f};
    const ushort_t* wb0 = wb + n*576;
    const ushort_t* wb1 = wb + (16 + n)*576;
    int colbase = wv*16 + n;

    #pragma unroll
    for (int s = 0; s < 18; ++s) {
        int tap  = s >> 1;
        int tapr = tap / 3, tapc = tap % 3;
        int coff = (s & 1)*32 + quad*8;
        bf16x8 a  = *(const bf16x8*)(win + (tapr*66 + colbase + tapc)*72 + coff);
        int kk = tap*64 + coff;
        bf16x8 b0 = *(const bf16x8*)(wb0 + kk);
        bf16x8 b1 = *(const bf16x8*)(wb1 + kk);
        acc0 = __builtin_amdgcn_mfma_f32_16x16x32_bf16(a, b0, acc0, 0, 0, 0);
        acc1 = __builtin_amdgcn_mfma_f32_16x16x32_bf16(a, b1, acc1, 0, 0, 0);
    }

    int prow = p0 + wv*16 + quad*4;
    #pragma unroll
    for (int r = 0; r < 4; ++r) {
        int p = prow + r;
        om[(size_t)p*28 + n] = acc0[r] + boff[n];
        int o1 = 16 + n;
        if (o1 < 18) {
            om[(size_t)p*28 + o1] = acc1[r] + boff[o1];
        } else if (o1 < 27) {
            float z = acc1[r] + bmsk[o1 - 18];
            om[(size_t)p*28 + o1] = 1.f / (1.f + expf(-z));
        } else if (o1 == 27) {
            om[(size_t)p*28 + 27] = 0.f;   // keep all of om defined
        }
    }
}

// ---------------------------------------------------------------------------
// Kernel 4: deformable sampling + bf16 MFMA GEMM, double-buffered samp LDS
// ---------------------------------------------------------------------------
__global__ __launch_bounds__(256) void deform_kernel(
    const ushort_t* __restrict__ xt, const float* __restrict__ om,
    const ushort_t* __restrict__ wt, float* __restrict__ out)
{
    __shared__ ushort_t samp[2*64*72];   // double-buffered [64p][72c] bf16

    int t = threadIdx.x;
    int lane = t & 63, wv = t >> 6;
    int p0 = blockIdx.x * 64;
    int b  = p0 >> 14;

    int pa = t >> 2, cg = t & 3;
    int gp = p0 + pa;
    int h_a = (gp >> 7) & 127, w_a = gp & 127;
    const float* omp = om + (size_t)gp * 28;
    const ushort_t* xbase = xt + ((size_t)b << 20);

    int n = lane & 15, quad = lane >> 4;
    floatx4 acc[4];
    #pragma unroll
    for (int i = 0; i < 4; ++i) acc[i] = (floatx4){0.f,0.f,0.f,0.f};
    const ushort_t* wrow = wt + (wv*16 + n)*576;

    for (int k = 0; k < 9; ++k) {
        ushort_t* sb = samp + (k & 1) * (64*72);

        // ---------------- phase A: bilinear sampling (fp32) ----------------
        int kr = k / 3, kc = k - kr*3;
        float dy = omp[2*k], dx = omp[2*k + 1], m = omp[18 + k];
        float py = (float)(h_a + kr - 1) + dy;
        float px = (float)(w_a + kc - 1) + dx;
        float y0f = floorf(py), x0f = floorf(px);
        float ly = py - y0f, lx = px - x0f;
        int y0 = (int)y0f, x0 = (int)x0f, y1 = y0 + 1, x1 = x0 + 1;
        float vy0 = ((unsigned)y0 < (unsigned)HH) ? 1.f : 0.f;
        float vy1 = ((unsigned)y1 < (unsigned)HH) ? 1.f : 0.f;
        float vx0 = ((unsigned)x0 < (unsigned)WW) ? 1.f : 0.f;
        float vx1 = ((unsigned)x1 < (unsigned)WW) ? 1.f : 0.f;

        float cw[4] = { (1.f-ly)*(1.f-lx)*vy0*vx0*m,
                        (1.f-ly)*lx      *vy0*vx1*m,
                        ly*(1.f-lx)      *vy1*vx0*m,
                        ly*lx            *vy1*vx1*m };
        int ys[4] = { y0, y0, y1, y1 };
        int xs[4] = { x0, x1, x0, x1 };

        float v[16];
        #pragma unroll
        for (int i = 0; i < 16; ++i) v[i] = 0.f;

        #pragma unroll
        for (int cn = 0; cn < 4; ++cn) {
            int yc = min(max(ys[cn], 0), HH-1);
            int xc = min(max(xs[cn], 0), WW-1);
            const uint4* cp = (const uint4*)(xbase + (((yc << 7) + xc) << 6) + cg*16);
            uint4 q0 = cp[0], q1 = cp[1];
            float f[16];
            unpack8(q0, f); unpack8(q1, f + 8);
            float wg = cw[cn];
            #pragma unroll
            for (int j = 0; j < 16; ++j) v[j] += wg * f[j];
        }

        // pack 16 fp32 -> 16 bf16, write 32B to sb[pa][cg*16..]
        {
            unsigned uu[8];
            #pragma unroll
            for (int j = 0; j < 8; ++j)
                uu[j] = (unsigned)f2b(v[2*j]) | ((unsigned)f2b(v[2*j+1]) << 16);
            uint4* dst = (uint4*)(sb + pa*72 + cg*16);
            dst[0] = make_uint4(uu[0], uu[1], uu[2], uu[3]);
            dst[1] = make_uint4(uu[4], uu[5], uu[6], uu[7]);
        }
        __syncthreads();   // writes of buf(k&1) visible; reads of buf((k-1)&1)
                           // finished >=2 barriers ago, so no WAR on re-use

        // ---------------- phase B: MFMA accumulate ----------------
        #pragma unroll
        for (int half = 0; half < 2; ++half) {
            bf16x8 bfrag = *(const bf16x8*)(wrow + k*64 + half*32 + quad*8);
            #pragma unroll
            for (int mt = 0; mt < 4; ++mt) {
                bf16x8 afrag = *(const bf16x8*)(sb + (mt*16 + n)*72 + half*32 + quad*8);
                acc[mt] = __builtin_amdgcn_mfma_f32_16x16x32_bf16(afrag, bfrag, acc[mt], 0, 0, 0);
            }
        }
        __syncthreads();   // phase-B reads of buf(k&1) done before it is
                           // rewritten at iteration k+2
    }

    int hw0 = p0 & 16383;
    float* op = out + ((size_t)b*OO + (wv*16 + n))*HW;
    #pragma unroll
    for (int mt = 0; mt < 4; ++mt) {
        float4 st = make_float4(acc[mt][0], acc[mt][1], acc[mt][2], acc[mt][3]);
        *(float4*)(op + hw0 + mt*16 + quad*4) = st;
    }
}

// ---------------------------------------------------------------------------
extern "C" void kernel_launch(void* const* d_in, const int* in_sizes, int n_in,
                              void* d_out, int out_size, void* d_ws, size_t ws_size,
                              hipStream_t stream)
{
    const float* x      = (const float*)d_in[0];
    const float* w_main = (const float*)d_in[1];
    const float* w_off  = (const float*)d_in[2];
    const float* b_off  = (const float*)d_in[3];
    const float* w_msk  = (const float*)d_in[4];
    const float* b_msk  = (const float*)d_in[5];
    float* out = (float*)d_out;

    unsigned char* ws = (unsigned char*)d_ws;
    ushort_t* xt = (ushort_t*)ws;
    float*    om = (float*)(ws + XT_BYTES);
    ushort_t* wt = (ushort_t*)(ws + XT_BYTES + OM_BYTES);
    ushort_t* wb = (ushort_t*)(ws + XT_BYTES + OM_BYTES + WT_BYTES);

    dim3 tgrid(BB*HH, WW/32, CC/32);
    dim3 tblock(32, 8);
    transpose_kernel<<<tgrid, tblock, 0, stream>>>(x, xt);

    repack_kernel<<<(36864 + 18432 + 255)/256, 256, 0, stream>>>(
        w_main, w_off, w_msk, wt, wb);

    conv27_kernel<<<NPIX/64, 256, 0, stream>>>(xt, wb, b_off, b_msk, om);

    deform_kernel<<<NPIX/64, 256, 0, stream>>>(xt, om, wt, out);
}

// Round 4
// 183.119 us; speedup vs baseline: 2.0998x; 1.0611x over previous
//
#include <hip/hip_runtime.h>
#include <math.h>

#define BB 8
#define CC 64
#define OO 64
#define HH 128
#define WW 128
#define HW (HH*WW)              // 16384
#define NPIX (BB*HW)            // 131072

typedef __bf16 bf16x8 __attribute__((ext_vector_type(8)));
typedef float floatx4 __attribute__((ext_vector_type(4)));
typedef unsigned short ushort_t;

// Workspace layout (bytes):
//  xt : bf16 NHWC [B][H][W][64]        16777216
//  om : fp32 [NPIX][28]                14680064
//  wt : bf16 [64][576]  (o, tap*64+c)     73728
//  wb : bf16 [32][576]  (o27pad, k)       36864
#define XT_BYTES  16777216
#define OM_BYTES  14680064
#define WT_BYTES  73728

__device__ __forceinline__ unsigned short f2b(float f) {
    unsigned u = __float_as_uint(f);
    u += 0x7fffu + ((u >> 16) & 1u);       // round-to-nearest-even
    return (unsigned short)(u >> 16);
}

__device__ __forceinline__ void unpack8(uint4 q, float* f) {
    f[0] = __uint_as_float(q.x << 16); f[1] = __uint_as_float(q.x & 0xffff0000u);
    f[2] = __uint_as_float(q.y << 16); f[3] = __uint_as_float(q.y & 0xffff0000u);
    f[4] = __uint_as_float(q.z << 16); f[5] = __uint_as_float(q.z & 0xffff0000u);
    f[6] = __uint_as_float(q.w << 16); f[7] = __uint_as_float(q.w & 0xffff0000u);
}

// ---------------------------------------------------------------------------
// Kernel 1: NCHW fp32 -> NHWC bf16 transpose, packed 4B stores
// grid (B*H, W/32), block 256. LDS tile [64c][33w] fp32.
// ---------------------------------------------------------------------------
__global__ __launch_bounds__(256) void transpose_kernel(
    const float* __restrict__ x, ushort_t* __restrict__ xt)
{
    __shared__ float tile[64][33];
    int bh = blockIdx.x;
    int w0 = blockIdx.y * 32;
    int b  = bh >> 7;
    int h  = bh & 127;
    int t  = threadIdx.x;
    int tx = t & 31;         // w lane
    int ty = t >> 5;         // 0..7

    #pragma unroll
    for (int j = 0; j < 8; ++j) {
        int c = ty * 8 + j;
        tile[c][tx] = x[(((size_t)(b*CC + c))*HH + h)*WW + (w0 + tx)];
    }
    __syncthreads();
    // write: lane = channel pair, 4B packed stores, 256B contiguous per wave
    #pragma unroll
    for (int j = 0; j < 4; ++j) {
        int w  = ty + 8*j;
        int cp = tx;
        unsigned u = (unsigned)f2b(tile[2*cp][w]) |
                     ((unsigned)f2b(tile[2*cp+1][w]) << 16);
        *(unsigned*)(xt + (((size_t)(b*HH + h))*WW + (w0 + w))*CC + 2*cp) = u;
    }
}

// ---------------------------------------------------------------------------
// Kernel 2: weight repack to bf16
// ---------------------------------------------------------------------------
__global__ __launch_bounds__(256) void repack_kernel(
    const float* __restrict__ wm, const float* __restrict__ woff,
    const float* __restrict__ wmask, ushort_t* __restrict__ wt,
    ushort_t* __restrict__ wb)
{
    int i = blockIdx.x * 256 + threadIdx.x;
    if (i < 36864) {
        int o = i / 576, k = i % 576, tap = k >> 6, c = k & 63;
        wt[i] = f2b(wm[o*576 + c*9 + tap]);
    }
    int j = i - 36864;
    if (j >= 0 && j < 18432) {
        int o = j / 576, k = j % 576, tap = k >> 6, c = k & 63;
        float v = 0.f;
        if (o < 18)      v = woff[o*576 + c*9 + tap];
        else if (o < 27) v = wmask[(o-18)*576 + c*9 + tap];
        wb[j] = f2b(v);
    }
}

// ---------------------------------------------------------------------------
// Kernel 3: conv3x3 -> 18 offsets + 9 sigmoid masks, bf16 MFMA, 16x16 tiles
// block = 256 thr = 4 waves, 256 pixels (16x16 tile). Window 18x18 px in LDS.
// wave wv: tile rows ty = wv*4..wv*4+3 (4 M-tiles), N=32, K=576 (18 steps).
// ---------------------------------------------------------------------------
__global__ __launch_bounds__(256) void conv27_kernel(
    const ushort_t* __restrict__ xt, const ushort_t* __restrict__ wb,
    const float* __restrict__ boff, const float* __restrict__ bmsk,
    float* __restrict__ om)
{
    __shared__ ushort_t win[18*18*72];     // [row][col][72ch-padded]
    int bid = blockIdx.x;
    int b  = bid >> 6;
    int th = (bid >> 3) & 7;
    int tw = bid & 7;
    int h0 = th * 16, w0 = tw * 16;
    int t = threadIdx.x;

    // stage 18x18 window (64ch, 8 x uint4 per pixel), zero-padded at borders
    for (int idx = t; idx < 18*18*8; idx += 256) {
        int r   = idx / 144;              // 18*8
        int rem = idx - r*144;
        int col = rem >> 3;
        int ch  = (rem & 7) << 3;
        int y = h0 + r - 1, x = w0 + col - 1;
        uint4 val = make_uint4(0,0,0,0);
        if ((unsigned)y < (unsigned)HH && (unsigned)x < (unsigned)WW)
            val = *(const uint4*)(xt + ((((size_t)b*HH + y)*WW + x) << 6) + ch);
        *(uint4*)(win + (r*18 + col)*72 + ch) = val;
    }
    __syncthreads();

    int lane = t & 63, wv = t >> 6;
    int n = lane & 15, quad = lane >> 4;
    const ushort_t* wb0 = wb + n*576;
    const ushort_t* wb1 = wb + (16 + n)*576;

    floatx4 acc0[4], acc1[4];
    #pragma unroll
    for (int mt = 0; mt < 4; ++mt) {
        acc0[mt] = (floatx4){0.f,0.f,0.f,0.f};
        acc1[mt] = (floatx4){0.f,0.f,0.f,0.f};
    }

    #pragma unroll
    for (int s = 0; s < 18; ++s) {
        int tap  = s >> 1;
        int tr   = tap / 3, tc = tap % 3;
        int coff = (s & 1)*32 + quad*8;
        int kk = tap*64 + coff;
        bf16x8 b0 = *(const bf16x8*)(wb0 + kk);
        bf16x8 b1 = *(const bf16x8*)(wb1 + kk);
        #pragma unroll
        for (int mt = 0; mt < 4; ++mt) {
            int ty = wv*4 + mt;
            // A row m = lane&15 = pixel tx within tile row ty
            bf16x8 a = *(const bf16x8*)(win + ((ty + tr)*18 + (n + tc))*72 + coff);
            acc0[mt] = __builtin_amdgcn_mfma_f32_16x16x32_bf16(a, b0, acc0[mt], 0, 0, 0);
            acc1[mt] = __builtin_amdgcn_mfma_f32_16x16x32_bf16(a, b1, acc1[mt], 0, 0, 0);
        }
    }

    // epilogue: D row = quad*4 + r = pixel tx, col = n = channel
    #pragma unroll
    for (int mt = 0; mt < 4; ++mt) {
        int ty = wv*4 + mt;
        #pragma unroll
        for (int r = 0; r < 4; ++r) {
            int tx = quad*4 + r;
            size_t p = ((size_t)(b*HH + h0 + ty))*WW + (w0 + tx);
            float* dst = om + p*28;
            dst[n] = acc0[mt][r] + boff[n];
            int o1 = 16 + n;
            if (o1 < 18) {
                dst[o1] = acc1[mt][r] + boff[o1];
            } else if (o1 < 27) {
                float z = acc1[mt][r] + bmsk[o1 - 18];
                dst[o1] = 1.f / (1.f + expf(-z));
            } else if (o1 == 27) {
                dst[27] = 0.f;
            }
        }
    }
}

// ---------------------------------------------------------------------------
// Kernel 4: deformable sampling + bf16 MFMA GEMM, 128 px/block, dbuf LDS
// phase A: 2 threads/pixel (32 ch each); phase B: wave owns 16 out channels,
// 8 M-tiles x 2 K-halves per tap.
// ---------------------------------------------------------------------------
__global__ __launch_bounds__(256) void deform_kernel(
    const ushort_t* __restrict__ xt, const float* __restrict__ om,
    const ushort_t* __restrict__ wt, float* __restrict__ out)
{
    __shared__ ushort_t samp[2*128*72];   // double-buffered [128p][72c] bf16

    int t = threadIdx.x;
    int lane = t & 63, wv = t >> 6;
    int p0 = blockIdx.x * 128;
    int b  = p0 >> 14;

    // phase-A role: 2 threads per pixel, 32 channels each
    int pa = t >> 1, hf = t & 1;
    int gp = p0 + pa;
    int h_a = (gp >> 7) & 127, w_a = gp & 127;
    const float* omp = om + (size_t)gp * 28;
    const ushort_t* xbase = xt + ((size_t)b << 20);

    int n = lane & 15, quad = lane >> 4;
    floatx4 acc[8];
    #pragma unroll
    for (int i = 0; i < 8; ++i) acc[i] = (floatx4){0.f,0.f,0.f,0.f};
    const ushort_t* wrow = wt + (wv*16 + n)*576;

    for (int k = 0; k < 9; ++k) {
        ushort_t* sb = samp + (k & 1) * (128*72);

        // ---------------- phase A: bilinear sampling (fp32) ----------------
        int kr = k / 3, kc = k - kr*3;
        float dy = omp[2*k], dx = omp[2*k + 1], m = omp[18 + k];
        float py = (float)(h_a + kr - 1) + dy;
        float px = (float)(w_a + kc - 1) + dx;
        float y0f = floorf(py), x0f = floorf(px);
        float ly = py - y0f, lx = px - x0f;
        int y0 = (int)y0f, x0 = (int)x0f, y1 = y0 + 1, x1 = x0 + 1;
        float vy0 = ((unsigned)y0 < (unsigned)HH) ? 1.f : 0.f;
        float vy1 = ((unsigned)y1 < (unsigned)HH) ? 1.f : 0.f;
        float vx0 = ((unsigned)x0 < (unsigned)WW) ? 1.f : 0.f;
        float vx1 = ((unsigned)x1 < (unsigned)WW) ? 1.f : 0.f;

        float cw[4] = { (1.f-ly)*(1.f-lx)*vy0*vx0*m,
                        (1.f-ly)*lx      *vy0*vx1*m,
                        ly*(1.f-lx)      *vy1*vx0*m,
                        ly*lx            *vy1*vx1*m };
        int ys[4] = { y0, y0, y1, y1 };
        int xs[4] = { x0, x1, x0, x1 };

        float v[32];
        #pragma unroll
        for (int i = 0; i < 32; ++i) v[i] = 0.f;

        #pragma unroll
        for (int cn = 0; cn < 4; ++cn) {
            int yc = min(max(ys[cn], 0), HH-1);
            int xc = min(max(xs[cn], 0), WW-1);
            const uint4* cp = (const uint4*)(xbase + (((yc << 7) + xc) << 6) + hf*32);
            uint4 q0 = cp[0], q1 = cp[1], q2 = cp[2], q3 = cp[3];
            float f[32];
            unpack8(q0, f); unpack8(q1, f + 8);
            unpack8(q2, f + 16); unpack8(q3, f + 24);
            float wg = cw[cn];
            #pragma unroll
            for (int j = 0; j < 32; ++j) v[j] += wg * f[j];
        }

        __syncthreads();   // previous phase-B reads of this buffer are done
        // pack 32 fp32 -> 32 bf16, write 64B to sb[pa][hf*32..]
        {
            unsigned uu[16];
            #pragma unroll
            for (int j = 0; j < 16; ++j)
                uu[j] = (unsigned)f2b(v[2*j]) | ((unsigned)f2b(v[2*j+1]) << 16);
            uint4* dst = (uint4*)(sb + pa*72 + hf*32);
            dst[0] = make_uint4(uu[0],  uu[1],  uu[2],  uu[3]);
            dst[1] = make_uint4(uu[4],  uu[5],  uu[6],  uu[7]);
            dst[2] = make_uint4(uu[8],  uu[9],  uu[10], uu[11]);
            dst[3] = make_uint4(uu[12], uu[13], uu[14], uu[15]);
        }
        __syncthreads();

        // ---------------- phase B: MFMA accumulate ----------------
        #pragma unroll
        for (int half = 0; half < 2; ++half) {
            bf16x8 bfrag = *(const bf16x8*)(wrow + k*64 + half*32 + quad*8);
            #pragma unroll
            for (int mt = 0; mt < 8; ++mt) {
                bf16x8 afrag = *(const bf16x8*)(sb + (mt*16 + n)*72 + half*32 + quad*8);
                acc[mt] = __builtin_amdgcn_mfma_f32_16x16x32_bf16(afrag, bfrag, acc[mt], 0, 0, 0);
            }
        }
    }

    // store: out[b][o][hw], o = wv*16 + n; D rows = pixel within M-tile
    int hw0 = p0 & 16383;
    float* op = out + ((size_t)b*OO + (wv*16 + n))*HW;
    #pragma unroll
    for (int mt = 0; mt < 8; ++mt) {
        float4 st = make_float4(acc[mt][0], acc[mt][1], acc[mt][2], acc[mt][3]);
        *(float4*)(op + hw0 + mt*16 + quad*4) = st;
    }
}

// ---------------------------------------------------------------------------
extern "C" void kernel_launch(void* const* d_in, const int* in_sizes, int n_in,
                              void* d_out, int out_size, void* d_ws, size_t ws_size,
                              hipStream_t stream)
{
    const float* x      = (const float*)d_in[0];
    const float* w_main = (const float*)d_in[1];
    const float* w_off  = (const float*)d_in[2];
    const float* b_off  = (const float*)d_in[3];
    const float* w_msk  = (const float*)d_in[4];
    const float* b_msk  = (const float*)d_in[5];
    float* out = (float*)d_out;

    unsigned char* ws = (unsigned char*)d_ws;
    ushort_t* xt = (ushort_t*)ws;
    float*    om = (float*)(ws + XT_BYTES);
    ushort_t* wt = (ushort_t*)(ws + XT_BYTES + OM_BYTES);
    ushort_t* wb = (ushort_t*)(ws + XT_BYTES + OM_BYTES + WT_BYTES);

    dim3 tgrid(BB*HH, WW/32);
    transpose_kernel<<<tgrid, 256, 0, stream>>>(x, xt);

    repack_kernel<<<(36864 + 18432 + 255)/256, 256, 0, stream>>>(
        w_main, w_off, w_msk, wt, wb);

    conv27_kernel<<<NPIX/256, 256, 0, stream>>>(xt, wb, b_off, b_msk, om);

    deform_kernel<<<NPIX/128, 256, 0, stream>>>(xt, om, wt, out);
}

// Round 5
// 162.903 us; speedup vs baseline: 2.3604x; 1.1241x over previous
//
#include <hip/hip_runtime.h>
#include <math.h>

#define BB 8
#define CC 64
#define OO 64
#define HH 128
#define WW 128
#define HW (HH*WW)              // 16384
#define NPIX (BB*HW)            // 131072

typedef __bf16 bf16x8 __attribute__((ext_vector_type(8)));
typedef float floatx4 __attribute__((ext_vector_type(4)));
typedef unsigned short ushort_t;

// Workspace layout (bytes):
//  xt : bf16 NHWC [B][H][W][64]        16777216
//  om : fp32 [NPIX][28]                14680064
//  wt : bf16 [64][576]  (o, tap*64+c)     73728
//  wb : bf16 [32][576]  (o27pad, k)       36864
#define XT_BYTES  16777216
#define OM_BYTES  14680064
#define WT_BYTES  73728

__device__ __forceinline__ unsigned short f2b(float f) {
    unsigned u = __float_as_uint(f);
    u += 0x7fffu + ((u >> 16) & 1u);       // round-to-nearest-even
    return (unsigned short)(u >> 16);
}

__device__ __forceinline__ void unpack8(uint4 q, float* f) {
    f[0] = __uint_as_float(q.x << 16); f[1] = __uint_as_float(q.x & 0xffff0000u);
    f[2] = __uint_as_float(q.y << 16); f[3] = __uint_as_float(q.y & 0xffff0000u);
    f[4] = __uint_as_float(q.z << 16); f[5] = __uint_as_float(q.z & 0xffff0000u);
    f[6] = __uint_as_float(q.w << 16); f[7] = __uint_as_float(q.w & 0xffff0000u);
}

// ---------------------------------------------------------------------------
// Kernel 1: NCHW fp32 -> NHWC bf16 transpose, packed 4B stores
// ---------------------------------------------------------------------------
__global__ __launch_bounds__(256) void transpose_kernel(
    const float* __restrict__ x, ushort_t* __restrict__ xt)
{
    __shared__ float tile[64][33];
    int bh = blockIdx.x;
    int w0 = blockIdx.y * 32;
    int b  = bh >> 7;
    int h  = bh & 127;
    int t  = threadIdx.x;
    int tx = t & 31;
    int ty = t >> 5;

    #pragma unroll
    for (int j = 0; j < 8; ++j) {
        int c = ty * 8 + j;
        tile[c][tx] = x[(((size_t)(b*CC + c))*HH + h)*WW + (w0 + tx)];
    }
    __syncthreads();
    #pragma unroll
    for (int j = 0; j < 4; ++j) {
        int w  = ty + 8*j;
        int cp = tx;
        unsigned u = (unsigned)f2b(tile[2*cp][w]) |
                     ((unsigned)f2b(tile[2*cp+1][w]) << 16);
        *(unsigned*)(xt + (((size_t)(b*HH + h))*WW + (w0 + w))*CC + 2*cp) = u;
    }
}

// ---------------------------------------------------------------------------
// Kernel 2: weight repack to bf16
// ---------------------------------------------------------------------------
__global__ __launch_bounds__(256) void repack_kernel(
    const float* __restrict__ wm, const float* __restrict__ woff,
    const float* __restrict__ wmask, ushort_t* __restrict__ wt,
    ushort_t* __restrict__ wb)
{
    int i = blockIdx.x * 256 + threadIdx.x;
    if (i < 36864) {
        int o = i / 576, k = i % 576, tap = k >> 6, c = k & 63;
        wt[i] = f2b(wm[o*576 + c*9 + tap]);
    }
    int j = i - 36864;
    if (j >= 0 && j < 18432) {
        int o = j / 576, k = j % 576, tap = k >> 6, c = k & 63;
        float v = 0.f;
        if (o < 18)      v = woff[o*576 + c*9 + tap];
        else if (o < 27) v = wmask[(o-18)*576 + c*9 + tap];
        wb[j] = f2b(v);
    }
}

// ---------------------------------------------------------------------------
// Kernel 3: conv3x3 -> 18 offsets + 9 sigmoid masks, bf16 MFMA, 16x16 tiles
// ---------------------------------------------------------------------------
__global__ __launch_bounds__(256) void conv27_kernel(
    const ushort_t* __restrict__ xt, const ushort_t* __restrict__ wb,
    const float* __restrict__ boff, const float* __restrict__ bmsk,
    float* __restrict__ om)
{
    __shared__ ushort_t win[18*18*72];
    int bid = blockIdx.x;
    int b  = bid >> 6;
    int th = (bid >> 3) & 7;
    int tw = bid & 7;
    int h0 = th * 16, w0 = tw * 16;
    int t = threadIdx.x;

    for (int idx = t; idx < 18*18*8; idx += 256) {
        int r   = idx / 144;
        int rem = idx - r*144;
        int col = rem >> 3;
        int ch  = (rem & 7) << 3;
        int y = h0 + r - 1, x = w0 + col - 1;
        uint4 val = make_uint4(0,0,0,0);
        if ((unsigned)y < (unsigned)HH && (unsigned)x < (unsigned)WW)
            val = *(const uint4*)(xt + ((((size_t)b*HH + y)*WW + x) << 6) + ch);
        *(uint4*)(win + (r*18 + col)*72 + ch) = val;
    }
    __syncthreads();

    int lane = t & 63, wv = t >> 6;
    int n = lane & 15, quad = lane >> 4;
    const ushort_t* wb0 = wb + n*576;
    const ushort_t* wb1 = wb + (16 + n)*576;

    floatx4 acc0[4], acc1[4];
    #pragma unroll
    for (int mt = 0; mt < 4; ++mt) {
        acc0[mt] = (floatx4){0.f,0.f,0.f,0.f};
        acc1[mt] = (floatx4){0.f,0.f,0.f,0.f};
    }

    #pragma unroll
    for (int s = 0; s < 18; ++s) {
        int tap  = s >> 1;
        int tr   = tap / 3, tc = tap % 3;
        int coff = (s & 1)*32 + quad*8;
        int kk = tap*64 + coff;
        bf16x8 b0 = *(const bf16x8*)(wb0 + kk);
        bf16x8 b1 = *(const bf16x8*)(wb1 + kk);
        #pragma unroll
        for (int mt = 0; mt < 4; ++mt) {
            int ty = wv*4 + mt;
            bf16x8 a = *(const bf16x8*)(win + ((ty + tr)*18 + (n + tc))*72 + coff);
            acc0[mt] = __builtin_amdgcn_mfma_f32_16x16x32_bf16(a, b0, acc0[mt], 0, 0, 0);
            acc1[mt] = __builtin_amdgcn_mfma_f32_16x16x32_bf16(a, b1, acc1[mt], 0, 0, 0);
        }
    }

    #pragma unroll
    for (int mt = 0; mt < 4; ++mt) {
        int ty = wv*4 + mt;
        #pragma unroll
        for (int r = 0; r < 4; ++r) {
            int tx = quad*4 + r;
            size_t p = ((size_t)(b*HH + h0 + ty))*WW + (w0 + tx);
            float* dst = om + p*28;
            dst[n] = acc0[mt][r] + boff[n];
            int o1 = 16 + n;
            if (o1 < 18) {
                dst[o1] = acc1[mt][r] + boff[o1];
            } else if (o1 < 27) {
                float z = acc1[mt][r] + bmsk[o1 - 18];
                dst[o1] = 1.f / (1.f + expf(-z));
            } else if (o1 == 27) {
                dst[27] = 0.f;
            }
        }
    }
}

// ---------------------------------------------------------------------------
// Kernel 4: deformable sampling + bf16 MFMA GEMM
// block = 256 thr, 64 pixels as an 8x8 2D tile (gather footprint ~13x13 px,
// L1/L2-resident). 4 threads/pixel, 16 ch each. samp dbuf 18.4KB -> high
// occupancy. om (dy,dx,m) software-pipelined one tap ahead.
// ---------------------------------------------------------------------------
__global__ __launch_bounds__(256) void deform_kernel(
    const ushort_t* __restrict__ xt, const float* __restrict__ om,
    const ushort_t* __restrict__ wt, float* __restrict__ out)
{
    __shared__ ushort_t samp[2*64*72];   // double-buffered [64p][72c] bf16

    int t = threadIdx.x;
    int lane = t & 63, wv = t >> 6;
    int bid = blockIdx.x;
    int b  = bid >> 8;
    int th = (bid >> 4) & 15;
    int tw = bid & 15;
    int h0 = th * 8, w0 = tw * 8;

    // phase-A role: 4 threads per pixel, 16 channels each; 8x8 pixel tile
    int pa = t >> 2, cg = t & 3;
    int ph = pa >> 3, pw = pa & 7;
    int h_a = h0 + ph, w_a = w0 + pw;
    const float* omp = om + (((size_t)(b*HH + h_a))*WW + w_a) * 28;
    const ushort_t* xbase = xt + ((size_t)b << 20);

    int n = lane & 15, quad = lane >> 4;
    floatx4 acc[4];
    #pragma unroll
    for (int i = 0; i < 4; ++i) acc[i] = (floatx4){0.f,0.f,0.f,0.f};
    const ushort_t* wrow = wt + (wv*16 + n)*576;

    float dy = omp[0], dx = omp[1], m = omp[18];   // tap-0 params

    for (int k = 0; k < 9; ++k) {
        ushort_t* sb = samp + (k & 1) * (64*72);

        // prefetch next tap's params (hide om latency behind this tap's work)
        float dy_n = 0.f, dx_n = 0.f, m_n = 0.f;
        if (k < 8) { dy_n = omp[2*k + 2]; dx_n = omp[2*k + 3]; m_n = omp[19 + k]; }

        // ---------------- phase A: bilinear sampling (fp32) ----------------
        int kr = k / 3, kc = k - kr*3;
        float py = (float)(h_a + kr - 1) + dy;
        float px = (float)(w_a + kc - 1) + dx;
        float y0f = floorf(py), x0f = floorf(px);
        float ly = py - y0f, lx = px - x0f;
        int y0 = (int)y0f, x0 = (int)x0f, y1 = y0 + 1, x1 = x0 + 1;
        float vy0 = ((unsigned)y0 < (unsigned)HH) ? 1.f : 0.f;
        float vy1 = ((unsigned)y1 < (unsigned)HH) ? 1.f : 0.f;
        float vx0 = ((unsigned)x0 < (unsigned)WW) ? 1.f : 0.f;
        float vx1 = ((unsigned)x1 < (unsigned)WW) ? 1.f : 0.f;

        float cw[4] = { (1.f-ly)*(1.f-lx)*vy0*vx0*m,
                        (1.f-ly)*lx      *vy0*vx1*m,
                        ly*(1.f-lx)      *vy1*vx0*m,
                        ly*lx            *vy1*vx1*m };
        int ys[4] = { y0, y0, y1, y1 };
        int xs[4] = { x0, x1, x0, x1 };

        dy = dy_n; dx = dx_n; m = m_n;   // rotate pipeline regs

        float v[16];
        #pragma unroll
        for (int i = 0; i < 16; ++i) v[i] = 0.f;

        #pragma unroll
        for (int cn = 0; cn < 4; ++cn) {
            int yc = min(max(ys[cn], 0), HH-1);
            int xc = min(max(xs[cn], 0), WW-1);
            const uint4* cp = (const uint4*)(xbase + (((yc << 7) + xc) << 6) + cg*16);
            uint4 q0 = cp[0], q1 = cp[1];
            float f[16];
            unpack8(q0, f); unpack8(q1, f + 8);
            float wg = cw[cn];
            #pragma unroll
            for (int j = 0; j < 16; ++j) v[j] += wg * f[j];
        }

        // pack 16 fp32 -> 16 bf16, write 32B to sb[pa][cg*16..]
        {
            unsigned uu[8];
            #pragma unroll
            for (int j = 0; j < 8; ++j)
                uu[j] = (unsigned)f2b(v[2*j]) | ((unsigned)f2b(v[2*j+1]) << 16);
            uint4* dst = (uint4*)(sb + pa*72 + cg*16);
            dst[0] = make_uint4(uu[0], uu[1], uu[2], uu[3]);
            dst[1] = make_uint4(uu[4], uu[5], uu[6], uu[7]);
        }
        __syncthreads();

        // ---------------- phase B: MFMA accumulate ----------------
        #pragma unroll
        for (int half = 0; half < 2; ++half) {
            bf16x8 bfrag = *(const bf16x8*)(wrow + k*64 + half*32 + quad*8);
            #pragma unroll
            for (int mt = 0; mt < 4; ++mt) {
                bf16x8 afrag = *(const bf16x8*)(sb + (mt*16 + n)*72 + half*32 + quad*8);
                acc[mt] = __builtin_amdgcn_mfma_f32_16x16x32_bf16(afrag, bfrag, acc[mt], 0, 0, 0);
            }
        }
        __syncthreads();
    }

    // store: out[b][o][h][w], o = wv*16 + n; D rows = local pixel id
    // p_local = mt*16 + quad*4 + r -> row = h0 + mt*2 + (quad>>1),
    //                                  col = w0 + (quad&1)*4 + r
    float* op = out + ((size_t)b*OO + (wv*16 + n))*HW;
    #pragma unroll
    for (int mt = 0; mt < 4; ++mt) {
        int row = h0 + mt*2 + (quad >> 1);
        int col = w0 + (quad & 1)*4;
        float4 st = make_float4(acc[mt][0], acc[mt][1], acc[mt][2], acc[mt][3]);
        *(float4*)(op + row*WW + col) = st;
    }
}

// ---------------------------------------------------------------------------
extern "C" void kernel_launch(void* const* d_in, const int* in_sizes, int n_in,
                              void* d_out, int out_size, void* d_ws, size_t ws_size,
                              hipStream_t stream)
{
    const float* x      = (const float*)d_in[0];
    const float* w_main = (const float*)d_in[1];
    const float* w_off  = (const float*)d_in[2];
    const float* b_off  = (const float*)d_in[3];
    const float* w_msk  = (const float*)d_in[4];
    const float* b_msk  = (const float*)d_in[5];
    float* out = (float*)d_out;

    unsigned char* ws = (unsigned char*)d_ws;
    ushort_t* xt = (ushort_t*)ws;
    float*    om = (float*)(ws + XT_BYTES);
    ushort_t* wt = (ushort_t*)(ws + XT_BYTES + OM_BYTES);
    ushort_t* wb = (ushort_t*)(ws + XT_BYTES + OM_BYTES + WT_BYTES);

    dim3 tgrid(BB*HH, WW/32);
    transpose_kernel<<<tgrid, 256, 0, stream>>>(x, xt);

    repack_kernel<<<(36864 + 18432 + 255)/256, 256, 0, stream>>>(
        w_main, w_off, w_msk, wt, wb);

    conv27_kernel<<<NPIX/256, 256, 0, stream>>>(xt, wb, b_off, b_msk, om);

    deform_kernel<<<NPIX/64, 256, 0, stream>>>(xt, om, wt, out);
}